// Round 1
// baseline (160.563 us; speedup 1.0000x reference)
//
#include <hip/hip_runtime.h>

#define OUT_F 11008
#define IN_F  4096
#define PKW   2048   // int32 words per weight row (each word = 1 byte = 2 nibbles)
#define BLKQ  128
#define MROWS 64

typedef __attribute__((ext_vector_type(8))) short          s16x8;
typedef __attribute__((ext_vector_type(8))) unsigned short u16x8;
typedef __attribute__((ext_vector_type(4))) float          f32x4;
typedef __attribute__((ext_vector_type(4))) int            i32x4;

__device__ __forceinline__ unsigned short f2bf(float f) {
    union { float f; unsigned u; } v; v.f = f;
    unsigned r = v.u + 0x8000u + ((v.u >> 16) & 1u);   // RNE-ish
    return (unsigned short)(r >> 16);
}

// Pre-swizzle x (64x4096 f32) into MFMA A-fragment order (bf16):
//   xf[((kb*4 + mt)*64 + lane)*8 + i] = x[mt*16 + (lane&15)][kb*32 + (lane>>4)*8 + i]
__global__ void prep_xfrag(const float* __restrict__ x, unsigned short* __restrict__ xf) {
    int kb   = blockIdx.x;            // 0..127 (k-window of 32)
    int t    = threadIdx.x;           // 0..255
    int mt   = t >> 6;
    int lane = t & 63;
    int m  = mt * 16 + (lane & 15);
    int k0 = kb * 32 + (lane >> 4) * 8;
    const float* xp = x + m * IN_F + k0;
    f32x4 a = *(const f32x4*)(xp);
    f32x4 b = *(const f32x4*)(xp + 4);
    u16x8 v;
    v[0] = f2bf(a[0]); v[1] = f2bf(a[1]); v[2] = f2bf(a[2]); v[3] = f2bf(a[3]);
    v[4] = f2bf(b[0]); v[5] = f2bf(b[1]); v[6] = f2bf(b[2]); v[7] = f2bf(b[3]);
    *(u16x8*)(xf + (size_t)((kb * 4 + mt) * 64 + lane) * 8) = v;
}

// Main: one WG per 16 output columns (o). 4 waves split K into quarters of 1024.
// Per 128-k round: coalesced packed-weight load -> in-reg dequant -> bf16 LDS tile,
// then each wave runs 4 k-subtiles x 4 m-tiles of mfma_f32_16x16x32_bf16.
__global__ __launch_bounds__(256) void qlin_main(
    const int*   __restrict__ wq,
    const float* __restrict__ scale,
    const float* __restrict__ zp,
    const float* __restrict__ bias,
    const unsigned short* __restrict__ xf,
    float* __restrict__ out)
{
    // 4 regions x 16 rows x 136 bf16 (pad 8) = 17408 B; reused as 16 KB f32 for reduction
    __shared__ __align__(16) unsigned short smem[4 * 16 * 136];

    const int t      = threadIdx.x;
    const int o_base = blockIdx.x * 16;
    const int wave   = t >> 6;        // this wave's K-quarter AND its staging region
    const int lane   = t & 63;

    // staging decomposition: thread stages 16 dwords (32 k) of one row, one region
    const int d      = t & 3;         // j-group: j in [d*32, d*32+32)
    const int row_r  = (t >> 2) & 15; // output row within tile
    const int region = t >> 6;        // == wave

    // per-thread dequant constants: s[j], zp*s[j] for j = d*32 + i  (j = k mod 128)
    float s[32], zs[32];
    {
        const float* sp = scale + (size_t)(o_base + row_r) * BLKQ + d * 32;
        const float* zpp = zp   + (size_t)(o_base + row_r) * BLKQ + d * 32;
        #pragma unroll
        for (int i = 0; i < 8; ++i) {
            f32x4 sv = *(const f32x4*)(sp  + i * 4);
            f32x4 zv = *(const f32x4*)(zpp + i * 4);
            #pragma unroll
            for (int c = 0; c < 4; ++c) {
                s [i * 4 + c] = sv[c];
                zs[i * 4 + c] = zv[c] * sv[c];
            }
        }
    }

    // global staging base (dword index); each round advances by 64 dwords (128 k)
    const int* wbase = wq + (size_t)(o_base + row_r) * PKW + region * 512 + d * 16;
    unsigned short* myw = smem + (region * 16 + row_r) * 136 + d * 32;

    f32x4 acc[4];
    #pragma unroll
    for (int mt = 0; mt < 4; ++mt) acc[mt] = (f32x4){0.f, 0.f, 0.f, 0.f};

    i32x4 wreg[4];
    #pragma unroll
    for (int q = 0; q < 4; ++q) wreg[q] = *(const i32x4*)(wbase + q * 4);

    const s16x8* xfv = (const s16x8*)xf;
    const unsigned short* bbase = smem + (wave * 16 + (lane & 15)) * 136;
    const int quad = lane >> 4;

    for (int tt = 0; tt < 8; ++tt) {
        __syncthreads();   // previous round's LDS reads complete

        // dequant 16 dwords -> 32 bf16, write 4x16B to LDS
        #pragma unroll
        for (int q = 0; q < 4; ++q) {
            u16x8 ob;
            #pragma unroll
            for (int pp = 0; pp < 4; ++pp) {
                unsigned dw = (unsigned)wreg[q][pp];
                int p = q * 4 + pp;                  // local dword 0..15
                float fh = (float)((dw >> 4) & 15u); // k = even (high nibble first)
                float fl = (float)(dw & 15u);
                ob[2 * pp]     = f2bf(fmaf(fh, s[2 * p],     -zs[2 * p]));
                ob[2 * pp + 1] = f2bf(fmaf(fl, s[2 * p + 1], -zs[2 * p + 1]));
            }
            *(u16x8*)(myw + q * 8) = ob;
        }

        // prefetch next round's packed weights
        if (tt < 7) {
            const int* nb = wbase + (tt + 1) * 64;
            #pragma unroll
            for (int q = 0; q < 4; ++q) wreg[q] = *(const i32x4*)(nb + q * 4);
        }

        __syncthreads();   // tile visible

        #pragma unroll
        for (int q0 = 0; q0 < 4; ++q0) {
            s16x8 bfrag = *(const s16x8*)(bbase + q0 * 32 + quad * 8);
            int kb = wave * 32 + tt * 4 + q0;        // global k-window
            #pragma unroll
            for (int mt = 0; mt < 4; ++mt) {
                s16x8 afrag = xfv[(size_t)(kb * 4 + mt) * 64 + lane];
                acc[mt] = __builtin_amdgcn_mfma_f32_16x16x32_bf16(afrag, bfrag, acc[mt], 0, 0, 0);
            }
        }
    }

    // reduce the 4 K-quarter waves via LDS, add bias, store
    __syncthreads();
    float* lf = (float*)smem;
    {
        const int col = lane & 15;
        #pragma unroll
        for (int mt = 0; mt < 4; ++mt) {
            #pragma unroll
            for (int r = 0; r < 4; ++r) {
                int m = mt * 16 + quad * 4 + r;      // C/D: col=lane&15, row=quad*4+reg
                lf[wave * 1024 + m * 16 + col] = acc[mt][r];
            }
        }
    }
    __syncthreads();
    #pragma unroll
    for (int p = 0; p < 4; ++p) {
        int e = p * 256 + t;
        int m = e >> 4, col = e & 15;
        float v = lf[e] + lf[1024 + e] + lf[2048 + e] + lf[3072 + e] + bias[o_base + col];
        out[(size_t)m * OUT_F + o_base + col] = v;
    }
}

extern "C" void kernel_launch(void* const* d_in, const int* in_sizes, int n_in,
                              void* d_out, int out_size, void* d_ws, size_t ws_size,
                              hipStream_t stream) {
    const float* x     = (const float*)d_in[0];
    const int*   wq    = (const int*)d_in[1];
    const float* scale = (const float*)d_in[2];
    const float* zpv   = (const float*)d_in[3];
    const float* bias  = (const float*)d_in[4];
    float* out = (float*)d_out;
    unsigned short* xf = (unsigned short*)d_ws;   // 512 KB A-fragment buffer

    prep_xfrag<<<128, 256, 0, stream>>>(x, xf);
    qlin_main<<<OUT_F / 16, 256, 0, stream>>>(wq, scale, zpv, bias, xf, out);
}